// Round 8
// baseline (1101.359 us; speedup 1.0000x reference)
//
#include <hip/hip_runtime.h>
#include <math.h>

#define CIN_    512
#define COUT_   512
#define LATENT_ 512
#define NB_     8
#define HH_     64
#define WW_     64

typedef float f32x16 __attribute__((ext_vector_type(16)));
typedef short bf16x8v __attribute__((ext_vector_type(8)));

__device__ inline unsigned short f2bf(float f) {
    union { float f; unsigned u; } v; v.f = f;
    unsigned r = v.u + 0x7fffu + ((v.u >> 16) & 1u);
    return (unsigned short)(r >> 16);
}

// Async global->LDS 16B copy. LDS dest must be wave-uniform base; HW adds lane*16.
__device__ __forceinline__ void gl_lds16(const void* g, void* l) {
    __builtin_amdgcn_global_load_lds(
        (const __attribute__((address_space(1))) unsigned int*)g,
        (__attribute__((address_space(3))) unsigned int*)l,
        16, 0, 0);
}

// ============ K1: fused wsq (blocks 0..1023) + wprep (1024..1311) + style (1312..1375)
// wprep emits wb in FRAGMENT-LINEAR layout:
//   wb[(tap*32+cb)*1024 + g*64 + l] (16B chunks), chunk = data for
//   co = g*32 + (l&31), ci(local) = (l>>5)*8 .. +7.
__global__ __launch_bounds__(256) void prep1(
    const float* __restrict__ w, const float* __restrict__ dlat,
    const float* __restrict__ mw, const float* __restrict__ mb,
    float* __restrict__ wsq, unsigned short* __restrict__ wb,
    float* __restrict__ s)
{
    __shared__ float smem[16 * 521];
    const float RC_W = 0.0147313912747197f;   // 1/sqrt(9*512)
    const float RC_S = 0.0441941738241592f;   // 1/sqrt(512)
    int b = blockIdx.x;
    int t = threadIdx.x;

    if (b < 1024) {
        int idx = b * 256 + t;
        float acc = 0.f;
#pragma unroll
        for (int tap = 0; tap < 9; ++tap) {
            float v = w[tap * (CIN_ * COUT_) + idx];
            acc += v * v;
        }
        wsq[idx] = acc;
    } else if (b < 1312) {
        int bb  = b - 1024;
        int tap = bb / 32;
        int cb  = bb % 32;
        for (int idx = t; idx < 16 * 512; idx += 256) {
            int ci = idx >> 9;
            int co = idx & 511;
            smem[ci * 521 + co] = w[((size_t)tap * 512 + cb * 16 + ci) * 512 + co];
        }
        __syncthreads();
        unsigned short* dst = wb + (size_t)(tap * 32 + cb) * 1024 * 8;
        for (int p = t; p < 2048; p += 256) {
            int l  = (p >> 1) & 63;
            int g  = p >> 7;
            int co = g * 32 + (l & 31);
            int ci = (l >> 5) * 8 + (p & 1) * 4;
            ushort4 o4;
            o4.x = f2bf(smem[(ci + 0) * 521 + co] * RC_W);
            o4.y = f2bf(smem[(ci + 1) * 521 + co] * RC_W);
            o4.z = f2bf(smem[(ci + 2) * 521 + co] * RC_W);
            o4.w = f2bf(smem[(ci + 3) * 521 + co] * RC_W);
            *(ushort4*)&dst[p * 4] = o4;
        }
    } else {
        int bb  = b - 1312;
        int n   = bb >> 3;
        int ci0 = (bb & 7) * 64;
        for (int i = t; i < LATENT_; i += 256) smem[i] = dlat[n * LATENT_ + i];
        __syncthreads();
        int cil  = t & 63;
        int part = t >> 6;
        const float* mwp = mw + ci0 + cil;
        float a0 = 0.f, a1 = 0.f;
        int l0 = part * 128;
#pragma unroll 4
        for (int l = l0; l < l0 + 128; l += 2) {
            a0 += smem[l]     * mwp[(size_t)l * CIN_];
            a1 += smem[l + 1] * mwp[(size_t)(l + 1) * CIN_];
        }
        smem[512 + part * 64 + cil] = a0 + a1;
        __syncthreads();
        if (t < 64) {
            float r = smem[512 + t] + smem[576 + t] + smem[640 + t] + smem[704 + t];
            s[n * CIN_ + ci0 + t] = r * RC_S + mb[ci0 + t] + 1.0f;
        }
    }
}

// ============ K2: fused demod (blocks 0..63) + xprep (64..1599)
__global__ __launch_bounds__(256) void prep2(
    const float* __restrict__ x, const float* __restrict__ s,
    const float* __restrict__ wsq, float* __restrict__ dmod,
    unsigned short* __restrict__ xt)
{
    __shared__ float smem[16 * 67 + 16];
    int b = blockIdx.x;
    int t = threadIdx.x;

    if (b < 64) {
        const float RCW2 = 1.0f / 4608.0f;
        int n   = b >> 3;
        int co0 = (b & 7) * 64;
        for (int i = t; i < CIN_; i += 256) { float v = s[n * CIN_ + i]; smem[i] = v * v; }
        __syncthreads();
        int col  = t & 63;
        int part = t >> 6;
        const float* wp = wsq + co0 + col;
        float a0 = 0.f, a1 = 0.f;
        int c0 = part * 128;
#pragma unroll 4
        for (int ci = c0; ci < c0 + 128; ci += 2) {
            a0 += smem[ci]     * wp[(size_t)ci * COUT_];
            a1 += smem[ci + 1] * wp[(size_t)(ci + 1) * COUT_];
        }
        smem[512 + part * 64 + col] = a0 + a1;
        __syncthreads();
        if (t < 64) {
            float r = smem[512 + t] + smem[576 + t] + smem[640 + t] + smem[704 + t];
            dmod[n * COUT_ + co0 + t] = rsqrtf(RCW2 * r + 1e-8f);
        }
    } else {
        int bb = b - 64;                 // n(8) x cb(32) x rg(6)
        int rg = bb % 6;
        int cb = (bb / 6) % 32;
        int n  = bb / (6 * 32);

        if (t < 16) smem[16 * 67 + t] = s[n * CIN_ + cb * 16 + t];

        int ci = t >> 4;
        int g0 = (t & 15) * 4;
        const float* srcbase = &x[(((size_t)(n * CIN_ + cb * 16 + ci)) * HH_) * WW_ + g0];
        int hp0 = rg * 11;

        float4 v = make_float4(0.f, 0.f, 0.f, 0.f);
        {
            int gh = hp0 - 1;
            if (gh >= 0 && gh < HH_) v = *(const float4*)&srcbase[(size_t)gh * WW_];
        }
        for (int hp = hp0; hp < hp0 + 11; ++hp) {
            int gh = hp - 1;
            bool rowok = (gh >= 0) && (gh < HH_);
            float4 vn = make_float4(0.f, 0.f, 0.f, 0.f);
            int ghn = gh + 1;
            if ((hp + 1 < hp0 + 11) && ghn >= 0 && ghn < HH_)
                vn = *(const float4*)&srcbase[(size_t)ghn * WW_];

            if (rowok) {
                float* dstl = &smem[ci * 67 + g0];
                dstl[0] = v.x; dstl[1] = v.y; dstl[2] = v.z; dstl[3] = v.w;
            }
            __syncthreads();

            unsigned short* dst = xt + (((size_t)(n * 32 + cb) * 66 + hp) * 66) * 16;
            for (int p = t; p < 264; p += 256) {
                int e   = p * 4;
                int wp_ = e >> 4;
                int cie = e & 15;
                int gw  = wp_ - 1;
                float vv0 = 0.f, vv1 = 0.f, vv2 = 0.f, vv3 = 0.f;
                if (rowok && gw >= 0 && gw < WW_) {
                    vv0 = smem[(cie + 0) * 67 + gw] * smem[16 * 67 + cie + 0];
                    vv1 = smem[(cie + 1) * 67 + gw] * smem[16 * 67 + cie + 1];
                    vv2 = smem[(cie + 2) * 67 + gw] * smem[16 * 67 + cie + 2];
                    vv3 = smem[(cie + 3) * 67 + gw] * smem[16 * 67 + cie + 3];
                }
                ushort4 o4;
                o4.x = f2bf(vv0); o4.y = f2bf(vv1); o4.z = f2bf(vv2); o4.w = f2bf(vv3);
                *(ushort4*)&dst[e] = o4;
            }
            __syncthreads();
            v = vn;
        }
    }
}

// ============ main conv: implicit GEMM on 32x32x16 bf16 MFMA
// R8: 256x256 block tile (16x16 spatial x 256 co), 4 waves each 128x128
// (acc[4][4] = 256 VGPR), 1 block/CU (grid=256, launch_bounds(256,1)).
// Halves LDS reads per MFMA (0.5KB) and per-CU staging -> LDS no longer
// oversubscribed vs MFMA pipe. xs layout [half][pos] makes A-frag ds_reads
// stride-1 (same conflict-free pattern as fragment-linear B).
// Schedule: triplet ping-pong (3 taps/step, 96 steps), stage-early +
// one __syncthreads per step (drain is free: DMA has full MFMA phase).
__global__ __launch_bounds__(256, 1) void conv_mfma(
    const unsigned short* __restrict__ xt,
    const unsigned short* __restrict__ wb,
    const float* __restrict__ dmod,
    float* __restrict__ out)
{
    __shared__ __align__(16) union {
        struct {
            unsigned short xs[2][768 * 8];       // 2 x 12288 B ([half 2][384 pos] chunks)
            unsigned short ws[2][3 * 512 * 8];   // 2 x 24576 B (triplet, frag-linear)
        } s;                                      // 73728 B
        float o[64 * 257];                        // 65792 B
    } sm;

    int b   = blockIdx.x;
    int cot = b & 1;              // co tile (2 of 256)
    int sw_ = (b >> 1) & 3;       // spatial col tile (4 of 16)
    int sh  = (b >> 3) & 3;       // spatial row tile (4 of 16)
    int n   = b >> 5;             // batch
    int h0 = sh * 16, w0 = sw_ * 16, co0 = cot * 256;

    int t    = threadIdx.x;
    int wv   = t >> 6, lane = t & 63;
    int mh   = wv >> 1, nh = wv & 1;     // 2M x 2N wave grid
    int l5   = lane & 31, half = lane >> 5;

    // ws staging offsets (per tap: 512 chunks, 2/thread)
    const int wsrc0 = t * 8, wsrc1 = (t + 256) * 8;
    const int wdst0 = (t & ~63) * 8, wdst1 = ((t + 256) & ~63) * 8;

    // xs staging: 768 chunks (2 half x 384 pos; pos<324 real), 3 passes.
    // LDS chunk li holds (half=li/384, pos=li%384 -> r=pos/18, c=pos%18);
    // source xt chunk = (r*66+c)*2 + half.
    int xsrc0_[3], xdst0_[3];
#pragma unroll
    for (int p = 0; p < 3; ++p) {
        int li  = t + p * 256;
        int hf  = (li >= 384) ? 1 : 0;
        int pos = li - hf * 384;
        if (pos > 323) pos = 323;           // pad clamp (data unused)
        int r = pos / 18, c = pos - r * 18;
        xsrc0_[p] = (r * 66 + c) * 16 + hf * 8;
        xdst0_[p] = ((t & ~63) + p * 256) * 8;
    }

    f32x16 acc[4][4];
#pragma unroll
    for (int ms = 0; ms < 4; ++ms)
#pragma unroll
        for (int ns = 0; ns < 4; ++ns)
#pragma unroll
            for (int i = 0; i < 16; ++i) acc[ms][ns][i] = 0.f;

    auto stage_tri = [&](int cb2, int j2, unsigned short* dbuf) {
#pragma unroll
        for (int tt = 0; tt < 3; ++tt) {
            int tap2 = j2 * 3 + tt;
            const unsigned short* tsrc =
                wb + ((size_t)(tap2 * 32 + cb2) * 1024 + cot * 512) * 8;
            gl_lds16(&tsrc[wsrc0], &dbuf[tt * 4096 + wdst0]);
            gl_lds16(&tsrc[wsrc1], &dbuf[tt * 4096 + wdst1]);
        }
    };
    auto stage_xs = [&](int cb2, unsigned short* dbuf) {
        const unsigned short* xb2 =
            xt + (((size_t)(n * 32 + cb2) * 66 + h0) * 66 + w0) * 16;
#pragma unroll
        for (int p = 0; p < 3; ++p)
            gl_lds16(&xb2[xsrc0_[p]], &dbuf[xdst0_[p]]);
    };

    unsigned short* wsR = (unsigned short*)sm.s.ws[0];
    unsigned short* wsS = (unsigned short*)sm.s.ws[1];
    unsigned short* xsR = (unsigned short*)sm.s.xs[0];
    unsigned short* xsP = (unsigned short*)sm.s.xs[1];

    // prologue
    stage_tri(0, 0, wsR);
    stage_xs(0, xsR);
    __syncthreads();

    for (int cb = 0; cb < 32; ++cb) {
#pragma unroll
        for (int j = 0; j < 3; ++j) {
            // stage next triplet (issued before compute; drained by step-end barrier)
            int snext = cb * 3 + j + 1;
            if (snext > 95) snext = 95;      // tail clamp (data unused)
            stage_tri(snext / 3, snext % 3, wsS);
            if (j == 1) {
                int cbn = (cb + 1 > 31) ? 31 : cb + 1;
                stage_xs(cbn, xsP);
            }

            __builtin_amdgcn_s_setprio(1);
#pragma unroll
            for (int tt = 0; tt < 3; ++tt) {
                bf16x8v bfr[4], afr[4];
                const unsigned short* wsb = wsR + tt * 4096;
#pragma unroll
                for (int ns = 0; ns < 4; ++ns)
                    bfr[ns] = *(const bf16x8v*)&wsb[((nh * 4 + ns) * 64 + lane) * 8];
#pragma unroll
                for (int ms = 0; ms < 4; ++ms) {
                    int pr = mh * 8 + ms * 2 + (l5 >> 4);
                    int pc = l5 & 15;
                    int pos = (pr + j) * 18 + (pc + tt);
                    afr[ms] = *(const bf16x8v*)&xsR[(half * 384 + pos) * 8];
                }
#pragma unroll
                for (int ms = 0; ms < 4; ++ms)
#pragma unroll
                    for (int ns = 0; ns < 4; ++ns)
                        acc[ms][ns] = __builtin_amdgcn_mfma_f32_32x32x16_bf16(
                            afr[ms], bfr[ns], acc[ms][ns], 0, 0, 0);
            }
            __builtin_amdgcn_s_setprio(0);

            { unsigned short* tmp = wsR; wsR = wsS; wsS = tmp; }
            __syncthreads();   // drains vmcnt+lgkmcnt; DMA had full MFMA phase
        }
        { unsigned short* tmp = xsR; xsR = xsP; xsP = tmp; }
    }

    // epilogue: demod + LDS transpose + coalesced float4 stores, 4 passes of 64 co.
    // acc C layout (32x32): col(co)=l5, row=(reg&3)+8*(reg>>2)+4*half.
    for (int pss = 0; pss < 4; ++pss) {
        __syncthreads();
        if (nh == (pss >> 1)) {
#pragma unroll
            for (int q = 0; q < 2; ++q) {
                int ns  = (pss & 1) * 2 + q;
                int bco = q * 32 + l5;
                float dv = dmod[n * COUT_ + co0 + pss * 64 + bco];
#pragma unroll
                for (int ms = 0; ms < 4; ++ms) {
#pragma unroll
                    for (int reg = 0; reg < 16; ++reg) {
                        int ml = (reg & 3) + 8 * (reg >> 2) + 4 * half;
                        int r  = mh * 8 + ms * 2 + (ml >> 4);   // 0..15
                        int c  = ml & 15;                        // 0..15
                        sm.o[bco * 257 + r * 16 + c] = acc[ms][ns][reg] * dv;
                    }
                }
            }
        }
        __syncthreads();
        for (int jj = t; jj < 4096; jj += 256) {
            int wq   = jj & 3;
            int row  = (jj >> 2) & 15;
            int bco2 = jj >> 6;              // 0..63
            int co = co0 + pss * 64 + bco2;
            const float* src = &sm.o[bco2 * 257 + row * 16 + wq * 4];
            float4 v = make_float4(src[0], src[1], src[2], src[3]);
            *(float4*)&out[(((size_t)n * COUT_ + co) * HH_ + h0 + row) * WW_ + w0 + wq * 4] = v;
        }
    }
}

extern "C" void kernel_launch(void* const* d_in, const int* in_sizes, int n_in,
                              void* d_out, int out_size, void* d_ws, size_t ws_size,
                              hipStream_t stream) {
    const float* x    = (const float*)d_in[0];
    const float* dlat = (const float*)d_in[1];
    const float* w    = (const float*)d_in[2];
    const float* mw   = (const float*)d_in[3];
    const float* mb   = (const float*)d_in[4];
    float* out = (float*)d_out;

    char* ws = (char*)d_ws;
    float* s    = (float*)(ws);                       // 4096 f
    float* dmod = (float*)(ws + 16384);               // 4096 f
    float* wsq  = (float*)(ws + 32768);               // 262144 f
    unsigned short* xt = (unsigned short*)(ws + 1081344);    // 17,842,176 u16
    unsigned short* wb = (unsigned short*)(ws + 36765696);   // 2,359,296 u16

    prep1<<<1376, 256, 0, stream>>>(w, dlat, mw, mb, wsq, wb, s);
    prep2<<<64 + NB_ * 32 * 6, 256, 0, stream>>>(x, s, wsq, dmod, xt);
    conv_mfma<<<256, 256, 0, stream>>>(xt, wb, dmod, out);
}

// Round 9
// 292.538 us; speedup vs baseline: 3.7648x; 3.7648x over previous
//
#include <hip/hip_runtime.h>
#include <math.h>

#define CIN_    512
#define COUT_   512
#define LATENT_ 512
#define NB_     8
#define HH_     64
#define WW_     64

typedef float f32x16 __attribute__((ext_vector_type(16)));
typedef short bf16x8v __attribute__((ext_vector_type(8)));

__device__ inline unsigned short f2bf(float f) {
    union { float f; unsigned u; } v; v.f = f;
    unsigned r = v.u + 0x7fffu + ((v.u >> 16) & 1u);
    return (unsigned short)(r >> 16);
}

// Async global->LDS 16B copy. LDS dest must be wave-uniform base; HW adds lane*16.
__device__ __forceinline__ void gl_lds16(const void* g, void* l) {
    __builtin_amdgcn_global_load_lds(
        (const __attribute__((address_space(1))) unsigned int*)g,
        (__attribute__((address_space(3))) unsigned int*)l,
        16, 0, 0);
}

// ============ K1: fused wsq (blocks 0..1023) + wprep (1024..1311) + style (1312..1375)
// wprep emits wb in FRAGMENT-LINEAR layout:
//   wb[(tap*32+cb)*1024 + g*64 + l] (16B chunks), chunk = data for
//   co = g*32 + (l&31), ci(local) = (l>>5)*8 .. +7.
__global__ __launch_bounds__(256) void prep1(
    const float* __restrict__ w, const float* __restrict__ dlat,
    const float* __restrict__ mw, const float* __restrict__ mb,
    float* __restrict__ wsq, unsigned short* __restrict__ wb,
    float* __restrict__ s)
{
    __shared__ float smem[16 * 521];
    const float RC_W = 0.0147313912747197f;   // 1/sqrt(9*512)
    const float RC_S = 0.0441941738241592f;   // 1/sqrt(512)
    int b = blockIdx.x;
    int t = threadIdx.x;

    if (b < 1024) {
        int idx = b * 256 + t;
        float acc = 0.f;
#pragma unroll
        for (int tap = 0; tap < 9; ++tap) {
            float v = w[tap * (CIN_ * COUT_) + idx];
            acc += v * v;
        }
        wsq[idx] = acc;
    } else if (b < 1312) {
        int bb  = b - 1024;
        int tap = bb / 32;
        int cb  = bb % 32;
        for (int idx = t; idx < 16 * 512; idx += 256) {
            int ci = idx >> 9;
            int co = idx & 511;
            smem[ci * 521 + co] = w[((size_t)tap * 512 + cb * 16 + ci) * 512 + co];
        }
        __syncthreads();
        unsigned short* dst = wb + (size_t)(tap * 32 + cb) * 1024 * 8;
        for (int p = t; p < 2048; p += 256) {
            int l  = (p >> 1) & 63;
            int g  = p >> 7;
            int co = g * 32 + (l & 31);
            int ci = (l >> 5) * 8 + (p & 1) * 4;
            ushort4 o4;
            o4.x = f2bf(smem[(ci + 0) * 521 + co] * RC_W);
            o4.y = f2bf(smem[(ci + 1) * 521 + co] * RC_W);
            o4.z = f2bf(smem[(ci + 2) * 521 + co] * RC_W);
            o4.w = f2bf(smem[(ci + 3) * 521 + co] * RC_W);
            *(ushort4*)&dst[p * 4] = o4;
        }
    } else {
        int bb  = b - 1312;
        int n   = bb >> 3;
        int ci0 = (bb & 7) * 64;
        for (int i = t; i < LATENT_; i += 256) smem[i] = dlat[n * LATENT_ + i];
        __syncthreads();
        int cil  = t & 63;
        int part = t >> 6;
        const float* mwp = mw + ci0 + cil;
        float a0 = 0.f, a1 = 0.f;
        int l0 = part * 128;
#pragma unroll 4
        for (int l = l0; l < l0 + 128; l += 2) {
            a0 += smem[l]     * mwp[(size_t)l * CIN_];
            a1 += smem[l + 1] * mwp[(size_t)(l + 1) * CIN_];
        }
        smem[512 + part * 64 + cil] = a0 + a1;
        __syncthreads();
        if (t < 64) {
            float r = smem[512 + t] + smem[576 + t] + smem[640 + t] + smem[704 + t];
            s[n * CIN_ + ci0 + t] = r * RC_S + mb[ci0 + t] + 1.0f;
        }
    }
}

// ============ K2: fused demod (blocks 0..63) + xprep (64..1599)
__global__ __launch_bounds__(256) void prep2(
    const float* __restrict__ x, const float* __restrict__ s,
    const float* __restrict__ wsq, float* __restrict__ dmod,
    unsigned short* __restrict__ xt)
{
    __shared__ float smem[16 * 67 + 16];
    int b = blockIdx.x;
    int t = threadIdx.x;

    if (b < 64) {
        const float RCW2 = 1.0f / 4608.0f;
        int n   = b >> 3;
        int co0 = (b & 7) * 64;
        for (int i = t; i < CIN_; i += 256) { float v = s[n * CIN_ + i]; smem[i] = v * v; }
        __syncthreads();
        int col  = t & 63;
        int part = t >> 6;
        const float* wp = wsq + co0 + col;
        float a0 = 0.f, a1 = 0.f;
        int c0 = part * 128;
#pragma unroll 4
        for (int ci = c0; ci < c0 + 128; ci += 2) {
            a0 += smem[ci]     * wp[(size_t)ci * COUT_];
            a1 += smem[ci + 1] * wp[(size_t)(ci + 1) * COUT_];
        }
        smem[512 + part * 64 + col] = a0 + a1;
        __syncthreads();
        if (t < 64) {
            float r = smem[512 + t] + smem[576 + t] + smem[640 + t] + smem[704 + t];
            dmod[n * COUT_ + co0 + t] = rsqrtf(RCW2 * r + 1e-8f);
        }
    } else {
        int bb = b - 64;                 // n(8) x cb(32) x rg(6)
        int rg = bb % 6;
        int cb = (bb / 6) % 32;
        int n  = bb / (6 * 32);

        if (t < 16) smem[16 * 67 + t] = s[n * CIN_ + cb * 16 + t];

        int ci = t >> 4;
        int g0 = (t & 15) * 4;
        const float* srcbase = &x[(((size_t)(n * CIN_ + cb * 16 + ci)) * HH_) * WW_ + g0];
        int hp0 = rg * 11;

        float4 v = make_float4(0.f, 0.f, 0.f, 0.f);
        {
            int gh = hp0 - 1;
            if (gh >= 0 && gh < HH_) v = *(const float4*)&srcbase[(size_t)gh * WW_];
        }
        for (int hp = hp0; hp < hp0 + 11; ++hp) {
            int gh = hp - 1;
            bool rowok = (gh >= 0) && (gh < HH_);
            float4 vn = make_float4(0.f, 0.f, 0.f, 0.f);
            int ghn = gh + 1;
            if ((hp + 1 < hp0 + 11) && ghn >= 0 && ghn < HH_)
                vn = *(const float4*)&srcbase[(size_t)ghn * WW_];

            if (rowok) {
                float* dstl = &smem[ci * 67 + g0];
                dstl[0] = v.x; dstl[1] = v.y; dstl[2] = v.z; dstl[3] = v.w;
            }
            __syncthreads();

            unsigned short* dst = xt + (((size_t)(n * 32 + cb) * 66 + hp) * 66) * 16;
            for (int p = t; p < 264; p += 256) {
                int e   = p * 4;
                int wp_ = e >> 4;
                int cie = e & 15;
                int gw  = wp_ - 1;
                float vv0 = 0.f, vv1 = 0.f, vv2 = 0.f, vv3 = 0.f;
                if (rowok && gw >= 0 && gw < WW_) {
                    vv0 = smem[(cie + 0) * 67 + gw] * smem[16 * 67 + cie + 0];
                    vv1 = smem[(cie + 1) * 67 + gw] * smem[16 * 67 + cie + 1];
                    vv2 = smem[(cie + 2) * 67 + gw] * smem[16 * 67 + cie + 2];
                    vv3 = smem[(cie + 3) * 67 + gw] * smem[16 * 67 + cie + 3];
                }
                ushort4 o4;
                o4.x = f2bf(vv0); o4.y = f2bf(vv1); o4.z = f2bf(vv2); o4.w = f2bf(vv3);
                *(ushort4*)&dst[e] = o4;
            }
            __syncthreads();
            v = vn;
        }
    }
}

// ============ main conv: implicit GEMM on 32x32x16 bf16 MFMA
// R9: identical to R8 (256x256 tile, 4 waves each 128x128, acc[4][4], 1 blk/CU)
// EXCEPT the epilogue pss loop is #pragma unroll'd. R8 indexed acc with the
// runtime pss variable -> LLVM demoted the whole 256-reg accumulator to
// scratch (6.4 GB HBM write traffic, MfmaUtil 6.5%). With static indices the
// acc lives in AGPRs (~256 AGPR + ~110 VGPR < 512/wave at 1 wave/SIMD).
__global__ __launch_bounds__(256, 1) void conv_mfma(
    const unsigned short* __restrict__ xt,
    const unsigned short* __restrict__ wb,
    const float* __restrict__ dmod,
    float* __restrict__ out)
{
    __shared__ __align__(16) union {
        struct {
            unsigned short xs[2][768 * 8];       // 2 x 12288 B ([half 2][384 pos] chunks)
            unsigned short ws[2][3 * 512 * 8];   // 2 x 24576 B (triplet, frag-linear)
        } s;                                      // 73728 B
        float o[64 * 257];                        // 65792 B
    } sm;

    int b   = blockIdx.x;
    int cot = b & 1;              // co tile (2 of 256)
    int sw_ = (b >> 1) & 3;       // spatial col tile (4 of 16)
    int sh  = (b >> 3) & 3;       // spatial row tile (4 of 16)
    int n   = b >> 5;             // batch
    int h0 = sh * 16, w0 = sw_ * 16, co0 = cot * 256;

    int t    = threadIdx.x;
    int wv   = t >> 6, lane = t & 63;
    int mh   = wv >> 1, nh = wv & 1;     // 2M x 2N wave grid
    int l5   = lane & 31, half = lane >> 5;

    // ws staging offsets (per tap: 512 chunks, 2/thread)
    const int wsrc0 = t * 8, wsrc1 = (t + 256) * 8;
    const int wdst0 = (t & ~63) * 8, wdst1 = ((t + 256) & ~63) * 8;

    // xs staging: 768 chunks (2 half x 384 pos; pos<324 real), 3 passes.
    // LDS chunk li holds (half=li/384, pos=li%384 -> r=pos/18, c=pos%18);
    // source xt chunk = (r*66+c)*2 + half.
    int xsrc0_[3], xdst0_[3];
#pragma unroll
    for (int p = 0; p < 3; ++p) {
        int li  = t + p * 256;
        int hf  = (li >= 384) ? 1 : 0;
        int pos = li - hf * 384;
        if (pos > 323) pos = 323;           // pad clamp (data unused)
        int r = pos / 18, c = pos - r * 18;
        xsrc0_[p] = (r * 66 + c) * 16 + hf * 8;
        xdst0_[p] = ((t & ~63) + p * 256) * 8;
    }

    f32x16 acc[4][4];
#pragma unroll
    for (int ms = 0; ms < 4; ++ms)
#pragma unroll
        for (int ns = 0; ns < 4; ++ns)
#pragma unroll
            for (int i = 0; i < 16; ++i) acc[ms][ns][i] = 0.f;

    auto stage_tri = [&](int cb2, int j2, unsigned short* dbuf) {
#pragma unroll
        for (int tt = 0; tt < 3; ++tt) {
            int tap2 = j2 * 3 + tt;
            const unsigned short* tsrc =
                wb + ((size_t)(tap2 * 32 + cb2) * 1024 + cot * 512) * 8;
            gl_lds16(&tsrc[wsrc0], &dbuf[tt * 4096 + wdst0]);
            gl_lds16(&tsrc[wsrc1], &dbuf[tt * 4096 + wdst1]);
        }
    };
    auto stage_xs = [&](int cb2, unsigned short* dbuf) {
        const unsigned short* xb2 =
            xt + (((size_t)(n * 32 + cb2) * 66 + h0) * 66 + w0) * 16;
#pragma unroll
        for (int p = 0; p < 3; ++p)
            gl_lds16(&xb2[xsrc0_[p]], &dbuf[xdst0_[p]]);
    };

    unsigned short* wsR = (unsigned short*)sm.s.ws[0];
    unsigned short* wsS = (unsigned short*)sm.s.ws[1];
    unsigned short* xsR = (unsigned short*)sm.s.xs[0];
    unsigned short* xsP = (unsigned short*)sm.s.xs[1];

    // prologue
    stage_tri(0, 0, wsR);
    stage_xs(0, xsR);
    __syncthreads();

    for (int cb = 0; cb < 32; ++cb) {
#pragma unroll
        for (int j = 0; j < 3; ++j) {
            // stage next triplet (issued before compute; drained by step-end barrier)
            int snext = cb * 3 + j + 1;
            if (snext > 95) snext = 95;      // tail clamp (data unused)
            stage_tri(snext / 3, snext % 3, wsS);
            if (j == 1) {
                int cbn = (cb + 1 > 31) ? 31 : cb + 1;
                stage_xs(cbn, xsP);
            }

            __builtin_amdgcn_s_setprio(1);
#pragma unroll
            for (int tt = 0; tt < 3; ++tt) {
                bf16x8v bfr[4], afr[4];
                const unsigned short* wsb = wsR + tt * 4096;
#pragma unroll
                for (int ns = 0; ns < 4; ++ns)
                    bfr[ns] = *(const bf16x8v*)&wsb[((nh * 4 + ns) * 64 + lane) * 8];
#pragma unroll
                for (int ms = 0; ms < 4; ++ms) {
                    int pr = mh * 8 + ms * 2 + (l5 >> 4);
                    int pc = l5 & 15;
                    int pos = (pr + j) * 18 + (pc + tt);
                    afr[ms] = *(const bf16x8v*)&xsR[(half * 384 + pos) * 8];
                }
#pragma unroll
                for (int ms = 0; ms < 4; ++ms)
#pragma unroll
                    for (int ns = 0; ns < 4; ++ns)
                        acc[ms][ns] = __builtin_amdgcn_mfma_f32_32x32x16_bf16(
                            afr[ms], bfr[ns], acc[ms][ns], 0, 0, 0);
            }
            __builtin_amdgcn_s_setprio(0);

            { unsigned short* tmp = wsR; wsR = wsS; wsS = tmp; }
            __syncthreads();   // drains vmcnt+lgkmcnt; DMA had full MFMA phase
        }
        { unsigned short* tmp = xsR; xsR = xsP; xsP = tmp; }
    }

    // epilogue: demod + LDS transpose + coalesced float4 stores, 4 passes of 64 co.
    // acc C layout (32x32): col(co)=l5, row=(reg&3)+8*(reg>>2)+4*half.
    // pss MUST be unrolled: runtime-indexed acc -> scratch (R8's 7x regression).
#pragma unroll
    for (int pss = 0; pss < 4; ++pss) {
        __syncthreads();
        if (nh == (pss >> 1)) {
#pragma unroll
            for (int q = 0; q < 2; ++q) {
                int ns  = (pss & 1) * 2 + q;
                int bco = q * 32 + l5;
                float dv = dmod[n * COUT_ + co0 + pss * 64 + bco];
#pragma unroll
                for (int ms = 0; ms < 4; ++ms) {
#pragma unroll
                    for (int reg = 0; reg < 16; ++reg) {
                        int ml = (reg & 3) + 8 * (reg >> 2) + 4 * half;
                        int r  = mh * 8 + ms * 2 + (ml >> 4);   // 0..15
                        int c  = ml & 15;                        // 0..15
                        sm.o[bco * 257 + r * 16 + c] = acc[ms][ns][reg] * dv;
                    }
                }
            }
        }
        __syncthreads();
        for (int jj = t; jj < 4096; jj += 256) {
            int wq   = jj & 3;
            int row  = (jj >> 2) & 15;
            int bco2 = jj >> 6;              // 0..63
            int co = co0 + pss * 64 + bco2;
            const float* src = &sm.o[bco2 * 257 + row * 16 + wq * 4];
            float4 v = make_float4(src[0], src[1], src[2], src[3]);
            *(float4*)&out[(((size_t)n * COUT_ + co) * HH_ + h0 + row) * WW_ + w0 + wq * 4] = v;
        }
    }
}

extern "C" void kernel_launch(void* const* d_in, const int* in_sizes, int n_in,
                              void* d_out, int out_size, void* d_ws, size_t ws_size,
                              hipStream_t stream) {
    const float* x    = (const float*)d_in[0];
    const float* dlat = (const float*)d_in[1];
    const float* w    = (const float*)d_in[2];
    const float* mw   = (const float*)d_in[3];
    const float* mb   = (const float*)d_in[4];
    float* out = (float*)d_out;

    char* ws = (char*)d_ws;
    float* s    = (float*)(ws);                       // 4096 f
    float* dmod = (float*)(ws + 16384);               // 4096 f
    float* wsq  = (float*)(ws + 32768);               // 262144 f
    unsigned short* xt = (unsigned short*)(ws + 1081344);    // 17,842,176 u16
    unsigned short* wb = (unsigned short*)(ws + 36765696);   // 2,359,296 u16

    prep1<<<1376, 256, 0, stream>>>(w, dlat, mw, mb, wsq, wb, s);
    prep2<<<64 + NB_ * 32 * 6, 256, 0, stream>>>(x, s, wsq, dmod, xt);
    conv_mfma<<<256, 256, 0, stream>>>(xt, wb, dmod, out);
}

// Round 11
// 264.665 us; speedup vs baseline: 4.1613x; 1.1053x over previous
//
#include <hip/hip_runtime.h>
#include <math.h>

#define CIN_    512
#define COUT_   512
#define LATENT_ 512
#define NB_     8
#define HH_     64
#define WW_     64

typedef float f32x16 __attribute__((ext_vector_type(16)));
typedef short bf16x8v __attribute__((ext_vector_type(8)));

__device__ inline unsigned short f2bf(float f) {
    union { float f; unsigned u; } v; v.f = f;
    unsigned r = v.u + 0x7fffu + ((v.u >> 16) & 1u);
    return (unsigned short)(r >> 16);
}

// Async global->LDS 16B copy. LDS dest must be wave-uniform base; HW adds lane*16.
__device__ __forceinline__ void gl_lds16(const void* g, void* l) {
    __builtin_amdgcn_global_load_lds(
        (const __attribute__((address_space(1))) unsigned int*)g,
        (__attribute__((address_space(3))) unsigned int*)l,
        16, 0, 0);
}

// ============ K1: fused wsq (blocks 0..1023) + wprep (1024..1311) + style (1312..1375)
// wprep emits wb in FRAGMENT-LINEAR layout:
//   wb[(tap*32+cb)*1024 + g*64 + l] (16B chunks), chunk = data for
//   co = g*32 + (l&31), ci(local) = (l>>5)*8 .. +7.
__global__ __launch_bounds__(256) void prep1(
    const float* __restrict__ w, const float* __restrict__ dlat,
    const float* __restrict__ mw, const float* __restrict__ mb,
    float* __restrict__ wsq, unsigned short* __restrict__ wb,
    float* __restrict__ s)
{
    __shared__ float smem[16 * 521];
    const float RC_W = 0.0147313912747197f;   // 1/sqrt(9*512)
    const float RC_S = 0.0441941738241592f;   // 1/sqrt(512)
    int b = blockIdx.x;
    int t = threadIdx.x;

    if (b < 1024) {
        int idx = b * 256 + t;
        float acc = 0.f;
#pragma unroll
        for (int tap = 0; tap < 9; ++tap) {
            float v = w[tap * (CIN_ * COUT_) + idx];
            acc += v * v;
        }
        wsq[idx] = acc;
    } else if (b < 1312) {
        int bb  = b - 1024;
        int tap = bb / 32;
        int cb  = bb % 32;
        for (int idx = t; idx < 16 * 512; idx += 256) {
            int ci = idx >> 9;
            int co = idx & 511;
            smem[ci * 521 + co] = w[((size_t)tap * 512 + cb * 16 + ci) * 512 + co];
        }
        __syncthreads();
        unsigned short* dst = wb + (size_t)(tap * 32 + cb) * 1024 * 8;
        for (int p = t; p < 2048; p += 256) {
            int l  = (p >> 1) & 63;
            int g  = p >> 7;
            int co = g * 32 + (l & 31);
            int ci = (l >> 5) * 8 + (p & 1) * 4;
            ushort4 o4;
            o4.x = f2bf(smem[(ci + 0) * 521 + co] * RC_W);
            o4.y = f2bf(smem[(ci + 1) * 521 + co] * RC_W);
            o4.z = f2bf(smem[(ci + 2) * 521 + co] * RC_W);
            o4.w = f2bf(smem[(ci + 3) * 521 + co] * RC_W);
            *(ushort4*)&dst[p * 4] = o4;
        }
    } else {
        int bb  = b - 1312;
        int n   = bb >> 3;
        int ci0 = (bb & 7) * 64;
        for (int i = t; i < LATENT_; i += 256) smem[i] = dlat[n * LATENT_ + i];
        __syncthreads();
        int cil  = t & 63;
        int part = t >> 6;
        const float* mwp = mw + ci0 + cil;
        float a0 = 0.f, a1 = 0.f;
        int l0 = part * 128;
#pragma unroll 4
        for (int l = l0; l < l0 + 128; l += 2) {
            a0 += smem[l]     * mwp[(size_t)l * CIN_];
            a1 += smem[l + 1] * mwp[(size_t)(l + 1) * CIN_];
        }
        smem[512 + part * 64 + cil] = a0 + a1;
        __syncthreads();
        if (t < 64) {
            float r = smem[512 + t] + smem[576 + t] + smem[640 + t] + smem[704 + t];
            s[n * CIN_ + ci0 + t] = r * RC_S + mb[ci0 + t] + 1.0f;
        }
    }
}

// ============ K2: fused demod (blocks 0..63) + xprep (64..1599)
// R11 == R10: xprep is BARRIER-FREE. Each wave owns a private 1104-float LDS
// slice and processes its own hp rows (wave wv takes hp = rg*11+wv, +4, +8).
// Ordering is per-wave vmcnt/lgkmcnt only -- zero __syncthreads in the loop.
__global__ __launch_bounds__(256) void prep2(
    const float* __restrict__ x, const float* __restrict__ s,
    const float* __restrict__ wsq, float* __restrict__ dmod,
    unsigned short* __restrict__ xt)
{
    __shared__ float smem[4 * 1104];   // 4 wave slices (16*67=1072 data + 16 s + pad)
    int b = blockIdx.x;
    int t = threadIdx.x;

    if (b < 64) {
        // ---- demod: d[n][co] = rsqrt(RC_W^2 * sum_ci s^2 * wsq + 1e-8) ----
        const float RCW2 = 1.0f / 4608.0f;
        int n   = b >> 3;
        int co0 = (b & 7) * 64;
        for (int i = t; i < CIN_; i += 256) { float v = s[n * CIN_ + i]; smem[i] = v * v; }
        __syncthreads();
        int col  = t & 63;
        int part = t >> 6;
        const float* wp = wsq + co0 + col;
        float a0 = 0.f, a1 = 0.f;
        int c0 = part * 128;
#pragma unroll 4
        for (int ci = c0; ci < c0 + 128; ci += 2) {
            a0 += smem[ci]     * wp[(size_t)ci * COUT_];
            a1 += smem[ci + 1] * wp[(size_t)(ci + 1) * COUT_];
        }
        smem[512 + part * 64 + col] = a0 + a1;
        __syncthreads();
        if (t < 64) {
            float r = smem[512 + t] + smem[576 + t] + smem[640 + t] + smem[704 + t];
            dmod[n * COUT_ + co0 + t] = rsqrtf(RCW2 * r + 1e-8f);
        }
    } else {
        int bb = b - 64;                 // n(8) x cb(32) x rg(6)
        int rg = bb % 6;
        int cb = (bb / 6) % 32;
        int n  = bb / (6 * 32);

        int wv   = t >> 6;
        int lane = t & 63;
        float* xsm = &smem[wv * 1104];   // wave-private slice

        if (lane < 16) xsm[1072 + lane] = s[n * CIN_ + cb * 16 + lane];

        const float* srcb = &x[((size_t)(n * CIN_ + cb * 16)) * (HH_ * WW_)];

        for (int hp = rg * 11 + wv; hp < rg * 11 + 11; hp += 4) {
            int gh = hp - 1;
            bool rowok = (gh >= 0) && (gh < HH_);
            if (rowok) {
                // wave loads 16ci x 64w row: 4 float4 per lane, coalesced 256B/ci
#pragma unroll
                for (int r = 0; r < 4; ++r) {
                    int idx = r * 64 + lane;
                    int ci  = idx >> 4;
                    int g0  = (idx & 15) * 4;
                    float4 v = *(const float4*)&srcb[(size_t)ci * (HH_ * WW_)
                                                     + (size_t)gh * WW_ + g0];
                    float* d = &xsm[ci * 67 + g0];
                    d[0] = v.x; d[1] = v.y; d[2] = v.z; d[3] = v.w;
                }
            }
            unsigned short* dst = xt + (((size_t)(n * 32 + cb) * 66 + hp) * 66) * 16;
            // 264 ushort4 per row, 8B/lane coalesced stores
#pragma unroll
            for (int r = 0; r < 5; ++r) {
                int p = r * 64 + lane;
                if (p < 264) {
                    int e   = p * 4;
                    int wp_ = e >> 4;
                    int cie = e & 15;
                    int gw  = wp_ - 1;
                    float vv0 = 0.f, vv1 = 0.f, vv2 = 0.f, vv3 = 0.f;
                    if (rowok && gw >= 0 && gw < WW_) {
                        vv0 = xsm[(cie + 0) * 67 + gw] * xsm[1072 + cie + 0];
                        vv1 = xsm[(cie + 1) * 67 + gw] * xsm[1072 + cie + 1];
                        vv2 = xsm[(cie + 2) * 67 + gw] * xsm[1072 + cie + 2];
                        vv3 = xsm[(cie + 3) * 67 + gw] * xsm[1072 + cie + 3];
                    }
                    ushort4 o4;
                    o4.x = f2bf(vv0); o4.y = f2bf(vv1);
                    o4.z = f2bf(vv2); o4.w = f2bf(vv3);
                    *(ushort4*)&dst[e] = o4;
                }
            }
        }
    }
}

// ============ main conv: implicit GEMM on 32x32x16 bf16 MFMA
// R11: verbatim R6 kernel (best measured: 133 us, MfmaUtil 54%), now with the
// CORRECT grid of 512 (R10 launched 1024 -> blocks 512..1023 wrote out[n=8..15]
// out of bounds -> core dump).
// Tap-pipelined schedule: 288 steps (32 cb x 9 taps); ws = 3-deep ring
// (8KB/tap), stage k+2 into ws[(tap+2)%3]; xs double-buffered by cb parity,
// prefetched at tap==4. Counted vmcnt(2)/(4) -- never 0 -- + one raw
// s_barrier per step.
__global__ __launch_bounds__(256, 2) void conv_mfma(
    const unsigned short* __restrict__ xt,
    const unsigned short* __restrict__ wb,
    const float* __restrict__ dmod,
    float* __restrict__ out)
{
    __shared__ __align__(16) union {
        struct {
            unsigned short xs[2][512 * 8];   // 2 x 8192 B (chunks 360.. are pad)
            unsigned short ws[3][4096];      // 3 x 8192 B
        } s;                                  // 40960 B
        float o[64 * 129];                    // 33024 B
    } sm;

    int b   = blockIdx.x;
    int cot = b & 1;              // 2 co tiles of 256
    int wt_ = (b >> 1) & 3;
    int ht  = (b >> 3) & 7;
    int n   = b >> 6;
    int h0 = ht * 8, w0 = wt_ * 16, co0 = cot * 256;

    int t    = threadIdx.x;
    int wv   = t >> 6, lane = t & 63;
    int mh   = wv >> 1, nh = wv & 1;     // 2M x 2N wave grid
    int l5   = lane & 31, half = lane >> 5;

    // Precomputed per-thread staging offsets (constant across steps).
    const int wsrc0 = t * 8, wsrc1 = (t + 256) * 8;
    const int wdst0 = (t & ~63) * 8, wdst1 = ((t + 256) & ~63) * 8;
    int m0 = t ^ ((t >> 3) & 7);
    int li1 = t + 256;
    int m1 = li1 ^ ((li1 >> 3) & 7); if (m1 > 359) m1 = 359;
    const int xsrc0 = (m0 / 36) * 1056 + (m0 % 36) * 8;
    const int xsrc1 = (m1 / 36) * 1056 + (m1 % 36) * 8;
    const int xdst0 = (t & ~63) * 8, xdst1 = ((t + 256) & ~63) * 8;

    f32x16 acc[2][4];
#pragma unroll
    for (int ms = 0; ms < 2; ++ms)
#pragma unroll
        for (int ns = 0; ns < 4; ++ns)
#pragma unroll
            for (int i = 0; i < 16; ++i) acc[ms][ns][i] = 0.f;

    // ---- staging helpers ----
    auto stage_ws = [&](int cb2, int tap2, int q) {
        const unsigned short* tsrc = wb + ((size_t)(tap2 * 32 + cb2) * 1024 + cot * 512) * 8;
        unsigned short* d = (unsigned short*)sm.s.ws[q];
        gl_lds16(&tsrc[wsrc0], &d[wdst0]);
        gl_lds16(&tsrc[wsrc1], &d[wdst1]);
    };
    auto stage_xs = [&](int cb2, int bq) {
        const unsigned short* xb2 = xt + (((size_t)(n * 32 + cb2) * 66 + h0) * 66 + w0) * 16;
        unsigned short* d = (unsigned short*)sm.s.xs[bq];
        gl_lds16(&xb2[xsrc0], &d[xdst0]);
        gl_lds16(&xb2[xsrc1], &d[xdst1]);
    };

    // ---- prologue: stage steps 0,1 + x tile for cb 0; full drain once ----
    stage_ws(0, 0, 0);
    stage_ws(0, 1, 1);
    stage_xs(0, 0);
    asm volatile("s_waitcnt vmcnt(0)" ::: "memory");
    __builtin_amdgcn_s_barrier();

    for (int cb = 0; cb < 32; ++cb) {
        const unsigned short* xsb = (const unsigned short*)sm.s.xs[cb & 1];
#pragma unroll
        for (int tap = 0; tap < 9; ++tap) {
            const int p  = tap % 3;            // read buffer (k%3 == tap%3)
            const int q2 = (tap + 2) % 3;      // stage target buffer
            const int kh = tap / 3, kw = tap % 3;

            // [A] LDS -> register fragments (compiler inserts lgkmcnt before MFMA)
            bf16x8v bfr[4], afr[2];
            const unsigned short* wsb = (const unsigned short*)sm.s.ws[p];
#pragma unroll
            for (int ns = 0; ns < 4; ++ns)
                bfr[ns] = *(const bf16x8v*)&wsb[((nh * 4 + ns) * 64 + lane) * 8];
#pragma unroll
            for (int ms = 0; ms < 2; ++ms) {
                int pr = mh * 4 + ms * 2 + (l5 >> 4);
                int pc = l5 & 15;
                int pos = (pr + kh) * 18 + (pc + kw);
                int ch  = pos * 2 + half;
                ch ^= (ch >> 3) & 7;
                afr[ms] = *(const bf16x8v*)&xsb[ch * 8];
            }

            // [B] stage ws for step k+2 (clamped at tail; uniform issue count)
            {
                int tap2 = tap + 2, cb2 = cb;
                if (tap2 >= 9) { tap2 -= 9; cb2 = cb + 1; }
                if (cb2 > 31) cb2 = 31;
                stage_ws(cb2, tap2, q2);
            }
            // [C] prefetch next cb's x tile mid-cb
            if (tap == 4) {
                int cb2 = (cb + 1 > 31) ? 31 : cb + 1;
                stage_xs(cb2, (cb + 1) & 1);
            }

            // [D] MFMA cluster
            __builtin_amdgcn_s_setprio(1);
#pragma unroll
            for (int ms = 0; ms < 2; ++ms)
#pragma unroll
                for (int ns = 0; ns < 4; ++ns)
                    acc[ms][ns] = __builtin_amdgcn_mfma_f32_32x32x16_bf16(
                        afr[ms], bfr[ns], acc[ms][ns], 0, 0, 0);
            __builtin_amdgcn_s_setprio(0);

            // [E] counted wait (stage issued LAST step must be complete) + barrier
            if (tap == 4) asm volatile("s_waitcnt vmcnt(4)" ::: "memory");
            else          asm volatile("s_waitcnt vmcnt(2)" ::: "memory");
            __builtin_amdgcn_s_barrier();
        }
    }

    // explicit drain: tail stages must land before LDS union is reused as o
    asm volatile("s_waitcnt vmcnt(0)" ::: "memory");

    // epilogue: demod + LDS transpose + coalesced float4 stores, 4 passes of 64 co.
    for (int pss = 0; pss < 4; ++pss) {
        __syncthreads();
        if (nh == (pss >> 1)) {
#pragma unroll
            for (int q = 0; q < 2; ++q) {
                int bco = q * 32 + l5;
                float dv = dmod[n * COUT_ + co0 + pss * 64 + bco];
#pragma unroll
                for (int ms = 0; ms < 2; ++ms) {
#pragma unroll
                    for (int reg = 0; reg < 16; ++reg) {
                        int ml = (reg & 3) + 8 * (reg >> 2) + 4 * half;
                        int m  = mh * 64 + ms * 32 + ml;
                        sm.o[bco * 129 + m] = acc[ms][(pss & 1) * 2 + q][reg] * dv;
                    }
                }
            }
        }
        __syncthreads();
        for (int j = t; j < 2048; j += 256) {
            int wq = j & 3;
            int pairidx = j >> 2;
            int row  = pairidx & 7;
            int bco2 = pairidx >> 3;
            int co = co0 + pss * 64 + bco2;
            const float* src = &sm.o[bco2 * 129 + row * 16 + wq * 4];
            float4 v = make_float4(src[0], src[1], src[2], src[3]);
            *(float4*)&out[(((size_t)n * COUT_ + co) * HH_ + h0 + row) * WW_ + w0 + wq * 4] = v;
        }
    }
}

extern "C" void kernel_launch(void* const* d_in, const int* in_sizes, int n_in,
                              void* d_out, int out_size, void* d_ws, size_t ws_size,
                              hipStream_t stream) {
    const float* x    = (const float*)d_in[0];
    const float* dlat = (const float*)d_in[1];
    const float* w    = (const float*)d_in[2];
    const float* mw   = (const float*)d_in[3];
    const float* mb   = (const float*)d_in[4];
    float* out = (float*)d_out;

    char* ws = (char*)d_ws;
    float* s    = (float*)(ws);                       // 4096 f
    float* dmod = (float*)(ws + 16384);               // 4096 f
    float* wsq  = (float*)(ws + 32768);               // 262144 f
    unsigned short* xt = (unsigned short*)(ws + 1081344);    // 17,842,176 u16
    unsigned short* wb = (unsigned short*)(ws + 36765696);   // 2,359,296 u16

    prep1<<<1376, 256, 0, stream>>>(w, dlat, mw, mb, wsq, wb, s);
    prep2<<<64 + NB_ * 32 * 6, 256, 0, stream>>>(x, s, wsq, dmod, xt);
    conv_mfma<<<512, 256, 0, stream>>>(xt, wb, dmod, out);
}